// Round 10
// baseline (128.312 us; speedup 1.0000x reference)
//
#include <hip/hip_runtime.h>

// ChebyshevAdditiveAngularMargin — two-phase, HBM-bound.
//   cosine = clip(outputs, -1+1e-7, 1-1e-7)
//   phi    = clenshaw(cosine, coeffs); phi = cosine > TH ? phi : cosine - MM
//   out[r][c] = 30 * (c == label[r] ? phi : cosine)   (targets one-hot, 1.0f)
//
// Ladder: R1 162 -> R4 145 -> R7 fused+NT 115.3 -> R9 split 127.7.
// R9 isolated: k2 (512MB pure 2-stream NT) ~5.8 TB/s vs fused 4.55 TB/s ->
// 3-stream interference confirmed; k1 (L3 scan) was the loss at ~38us
// (latency-bound grid-stride). R10: k1 exact-cover, one block per row,
// 8 batched cached loads/thread (8 in flight, no loop dependence).
// k2 unchanged from R9.

namespace {

typedef float f32x4 __attribute__((ext_vector_type(4)));

constexpr float kClipLo = -0.9999999f;   // -1 + 1e-7 rounded to f32
constexpr float kClipHi =  0.9999999f;   //  1 - 1e-7 rounded to f32
constexpr float kTH     = -0.98006657784124163f;  // cos(pi - 0.2)
constexpr float kMM     =  0.039733866159012243f; // sin(pi - 0.2) * 0.2
constexpr float kSCALE  = 30.0f;
constexpr int   kDegree = 30;            // 31 coefficients
constexpr int   kC      = 8192;          // columns per row
constexpr int   kPerThread = 4;          // float4s per thread per array (k2)

__device__ __forceinline__ float clenshaw_phi(float x, const float* __restrict__ coeffs) {
    // b_k = c_k + 2x*b_{k+1} - b_{k+2}, k = DEGREE..0;  f(x) = b_0 - x*b_1
    const float x2 = 2.0f * x;
    float b1 = 0.0f, b2 = 0.0f;
#pragma unroll
    for (int k = kDegree; k >= 0; --k) {
        float b = coeffs[k] + x2 * b1 - b2;
        b2 = b1;
        b1 = b;
    }
    return b1 - b2 * x;
}

// ---- k1: one block per row. 2048 float4 per row / 256 threads = 8 batched
// cached loads per thread (all independent, 8 in flight). Exactly one thread
// per block finds the 1.0 and writes labels[row]. targets stays L3-resident
// (nothing else allocates L3: k2 is fully nontemporal).
__global__ __launch_bounds__(256) void scan_labels_kernel(
    const f32x4* __restrict__ targets4,
    int*         __restrict__ labels) {
    const int row  = blockIdx.x;
    const int base = row * (kC / 4) + threadIdx.x;

    f32x4 t[8];
#pragma unroll
    for (int u = 0; u < 8; ++u) t[u] = targets4[base + 256 * u];

#pragma unroll
    for (int u = 0; u < 8; ++u) {
#pragma unroll
        for (int j = 0; j < 4; ++j) {
            if (t[u][j] != 0.0f) {   // taken by exactly 1 of 2048 lanes/block
                labels[row] = (threadIdx.x + 256 * u) * 4 + j;
            }
        }
    }
}

// ---- k2: pure 2-stream NT kernel. Each block covers 1024 consecutive
// float4 = half a row; row (= blockIdx.x>>1) and label are block-uniform.
__global__ __launch_bounds__(256) void cheb_aam_kernel(
    const f32x4* __restrict__ outputs4,
    const int*   __restrict__ labels,
    const float* __restrict__ coeffs,
    f32x4*       __restrict__ dst4) {
    const int base   = blockIdx.x * (256 * kPerThread) + threadIdx.x;
    const int row    = blockIdx.x >> 1;            // 2048 float4 per row
    const int hotIdx = row * kC + labels[row];     // global float index of the 1

    f32x4 o[kPerThread];
#pragma unroll
    for (int u = 0; u < kPerThread; ++u)
        o[u] = __builtin_nontemporal_load(&outputs4[base + 256 * u]);

#pragma unroll
    for (int u = 0; u < kPerThread; ++u) {
        const int i4 = base + 256 * u;
        f32x4 r;
#pragma unroll
        for (int j = 0; j < 4; ++j) {
            const float x = fminf(fmaxf(o[u][j], kClipLo), kClipHi);
            float rv = x;  // cold path: out = cosine
            if (i4 * 4 + j == hotIdx) {
                // hot: exactly one element per row
                rv = (x > kTH) ? clenshaw_phi(x, coeffs) : (x - kMM);
            }
            r[j] = kSCALE * rv;
        }
        __builtin_nontemporal_store(r, &dst4[i4]);
    }
}

}  // namespace

extern "C" void kernel_launch(void* const* d_in, const int* in_sizes, int n_in,
                              void* d_out, int out_size, void* d_ws, size_t ws_size,
                              hipStream_t stream) {
    const float* outputs = (const float*)d_in[0];
    const float* targets = (const float*)d_in[1];
    const float* coeffs  = (const float*)d_in[2];
    float* dst  = (float*)d_out;
    int* labels = (int*)d_ws;                     // 8192 ints = 32 KB

    const int n  = out_size;                      // 8192*8192
    const int n4 = n / 4;
    const int rows = n / kC;                      // 8192

    // k1: one block per row, 8-deep batched cached loads (L3-served)
    scan_labels_kernel<<<rows, 256, 0, stream>>>(
        (const f32x4*)targets, labels);

    // k2: 2-stream NT elementwise (16384 blocks, 4 float4/thread)
    const int perBlock = 256 * kPerThread;        // 1024 float4 / block
    const int grid = (n4 + perBlock - 1) / perBlock;
    cheb_aam_kernel<<<grid, 256, 0, stream>>>(
        (const f32x4*)outputs, labels, coeffs, (f32x4*)dst);
}

// Round 11
// 115.368 us; speedup vs baseline: 1.1122x; 1.1122x over previous
//
#include <hip/hip_runtime.h>

// ChebyshevAdditiveAngularMargin — HBM/fabric-bound elementwise op.
//   cosine = clip(outputs, -1+1e-7, 1-1e-7)
//   phi    = clenshaw(cosine, coeffs)            (Chebyshev, degree 30)
//   phi    = cosine > TH ? phi : cosine - MM
//   out    = 30 * (targets*phi + (1-targets)*cosine)   (targets one-hot)
//
// FINAL (revert to R7, best = 115.3us). Ladder: R1 grid-stride 162 ->
// R4 one-shot 4xfloat4 batched 145 -> R7 +NT on outputs/dst 115.3.
// Nulls/regressions: R5 8x/thread 149; R6 persistent dbuf 161; R8 forced
// 16-deep MLP 117 (null); R9/R10 two-phase split (labels scan + 2-stream)
// 128 both — scan is BW-floored at ~6.4 TB/s, proving L3->CU fabric serves
// ~= HBM rate, so total-lines-moved (768MB/call) is the only currency.
// Ceiling: 768MB / ~7 TB/s =~ 110us; this kernel = 6.66 TB/s aggregate
// (~95%). targets (256MB, exactly L3-sized) stays cached; the two
// zero-reuse streams bypass via nontemporal hints.

namespace {

typedef float f32x4 __attribute__((ext_vector_type(4)));

constexpr float kClipLo = -0.9999999f;   // -1 + 1e-7 rounded to f32
constexpr float kClipHi =  0.9999999f;   //  1 - 1e-7 rounded to f32
constexpr float kTH     = -0.98006657784124163f;  // cos(pi - 0.2)
constexpr float kMM     =  0.039733866159012243f; // sin(pi - 0.2) * 0.2
constexpr float kSCALE  = 30.0f;
constexpr int   kDegree = 30;            // 31 coefficients
constexpr int   kPerThread = 4;          // float4s per thread per array

__device__ __forceinline__ float clenshaw_phi(float x, const float* __restrict__ coeffs) {
    // b_k = c_k + 2x*b_{k+1} - b_{k+2}, k = DEGREE..0;  f(x) = b_0 - x*b_1
    const float x2 = 2.0f * x;
    float b1 = 0.0f, b2 = 0.0f;
#pragma unroll
    for (int k = kDegree; k >= 0; --k) {
        float b = coeffs[k] + x2 * b1 - b2;
        b2 = b1;
        b1 = b;
    }
    return b1 - b2 * x;
}

__device__ __forceinline__ f32x4 process4(f32x4 o, f32x4 t,
                                          const float* __restrict__ coeffs) {
    f32x4 r;
#pragma unroll
    for (int j = 0; j < 4; ++j) {
        const float x = fminf(fmaxf(o[j], kClipLo), kClipHi);
        float rv = x;  // targets == 0 path: out = cosine
        if (t[j] != 0.0f) {
            // rare path: ~1 element per 8192
            const float phi = (x > kTH) ? clenshaw_phi(x, coeffs) : (x - kMM);
            rv = t[j] * phi + (1.0f - t[j]) * x;
        }
        r[j] = kSCALE * rv;
    }
    return r;
}

// One shot per thread: kPerThread coalesced float4 per array, stride-256
// within the block. All loads issued before any use. outputs/dst are
// nontemporal (zero reuse); targets cached (L3-resident across replays).
__global__ __launch_bounds__(256) void cheb_aam_kernel(
    const f32x4* __restrict__ outputs4,
    const f32x4* __restrict__ targets4,
    const float* __restrict__ coeffs,
    f32x4*       __restrict__ dst4,
    int n4) {
    const int base = blockIdx.x * (256 * kPerThread) + threadIdx.x;

    if (base + 256 * (kPerThread - 1) < n4) {  // uniform fast path
        f32x4 o[kPerThread], t[kPerThread];
#pragma unroll
        for (int u = 0; u < kPerThread; ++u)
            o[u] = __builtin_nontemporal_load(&outputs4[base + 256 * u]);
#pragma unroll
        for (int u = 0; u < kPerThread; ++u)
            t[u] = targets4[base + 256 * u];
#pragma unroll
        for (int u = 0; u < kPerThread; ++u) {
            f32x4 r = process4(o[u], t[u], coeffs);
            __builtin_nontemporal_store(r, &dst4[base + 256 * u]);
        }
    } else {  // tail block (not taken for 8192x8192)
#pragma unroll
        for (int u = 0; u < kPerThread; ++u) {
            const int i = base + 256 * u;
            if (i < n4) {
                f32x4 r = process4(__builtin_nontemporal_load(&outputs4[i]),
                                   targets4[i], coeffs);
                __builtin_nontemporal_store(r, &dst4[i]);
            }
        }
    }
}

}  // namespace

extern "C" void kernel_launch(void* const* d_in, const int* in_sizes, int n_in,
                              void* d_out, int out_size, void* d_ws, size_t ws_size,
                              hipStream_t stream) {
    const float* outputs = (const float*)d_in[0];
    const float* targets = (const float*)d_in[1];
    const float* coeffs  = (const float*)d_in[2];
    float* dst = (float*)d_out;

    const int n  = out_size;       // 8192*8192, divisible by 4
    const int n4 = n / 4;

    const int block = 256;
    const int perBlock = block * kPerThread;           // 1024 float4 / block
    const int grid = (n4 + perBlock - 1) / perBlock;   // 16384 for 8192^2

    cheb_aam_kernel<<<grid, block, 0, stream>>>(
        (const f32x4*)outputs, (const f32x4*)targets, coeffs,
        (f32x4*)dst, n4);
}